// Round 6
// baseline (22.432 us; speedup 1.0000x reference)
//
#include <hip/hip_runtime.h>

#define DEV __device__ __forceinline__

typedef _Float16 h2 __attribute__((ext_vector_type(2)));
typedef float    f2 __attribute__((ext_vector_type(2)));

DEV float fast_rcp(float x) { return __builtin_amdgcn_rcpf(x); }

DEV float fexp2(float x) {
#if __has_builtin(__builtin_amdgcn_exp2f)
    return __builtin_amdgcn_exp2f(x);
#else
    float r; asm("v_exp_f32 %0, %1" : "=v"(r) : "v"(x)); return r;
#endif
}

DEV float dot2acc(h2 a, h2 b, float c) {
#if __has_builtin(__builtin_amdgcn_fdot2)
    return __builtin_amdgcn_fdot2(a, b, c, false);
#else
    return c + (float)a.x * (float)b.x + (float)a.y * (float)b.y;
#endif
}

// tanh(x) = 1 - 2/(exp2(2*log2e*x)+1); saturates correctly at +/-inf.
DEV float fast_tanh(float x) {
    float e = fexp2(x * 2.885390082f);
    return 1.0f - 2.0f * fast_rcp(e + 1.0f);
}
DEV float fast_sigmoid(float x) {
    return fast_rcp(1.0f + fexp2(x * -1.442695041f));
}

// MLP layer with input-pair packing: (w[o][2i], w[o][2i+1]) is contiguous in
// the row-major weights -> one uniform 64-bit s_load feeds v_pk_fma_f32.
// Accumulates even/odd partial sums in a packed f2, one horizontal add at end.
template <int IN, int OUT, bool HAS_BIAS, bool TANH>
DEV void layer_pk(const float* __restrict__ w, const float* __restrict__ b,
                  const float (&in)[IN], float (&out)[OUT]) {
    f2 acc[OUT];
    #pragma unroll
    for (int o = 0; o < OUT; ++o) acc[o] = f2{HAS_BIAS ? b[o] : 0.0f, 0.0f};
    #pragma unroll
    for (int ip = 0; ip < IN / 2; ++ip) {
        f2 in2 = {in[2 * ip], in[2 * ip + 1]};
        #pragma unroll
        for (int o = 0; o < OUT; ++o) {
            f2 w2 = *reinterpret_cast<const f2*>(w + o * IN + 2 * ip);
            acc[o] = w2 * in2 + acc[o];   // v_pk_fma_f32 (contract=fast)
        }
    }
    #pragma unroll
    for (int o = 0; o < OUT; ++o) {
        float s = acc[o].x + acc[o].y;
        out[o] = TANH ? fast_tanh(s) : s;
    }
}

__global__ __launch_bounds__(512)
void qcnn_fused_kernel(const float* __restrict__ x,
                       const float* __restrict__ w_fm, const float* __restrict__ b_fm,
                       const float* __restrict__ w_c1, const float* __restrict__ b_c1,
                       const float* __restrict__ w_p1, const float* __restrict__ b_p1,
                       const float* __restrict__ w_c2, const float* __restrict__ b_c2,
                       const float* __restrict__ w_p2, const float* __restrict__ b_p2,
                       const float* __restrict__ w_c3, const float* __restrict__ b_c3,
                       const float* __restrict__ w_q,  const float* __restrict__ w_k,
                       const float* __restrict__ w_v,
                       const float* __restrict__ w_fc, const float* __restrict__ b_fc,
                       float* __restrict__ out) {
    const int t     = threadIdx.x;          // 0..511
    const int bb    = t >> 7;               // sub-batch 0..3 within block
    const int tok   = t & 127;              // token 0..127
    const int batch = blockIdx.x * 4 + bb;  // 0..2047

    // per-sub-batch KV: x=k01(fp16x2) y=k23(fp16x2) z=u(f32) w=pad
    __shared__ uint4 kvbuf[4][128];

    // ---- load x[batch][tok][0:8] (coalesced, 32 B/thread) ----
    const float* xp = x + ((size_t)batch * 128 + tok) * 8;
    float4 x0 = *reinterpret_cast<const float4*>(xp);
    float4 x1 = *reinterpret_cast<const float4*>(xp + 4);
    float xin[8] = {x0.x, x0.y, x0.z, x0.w, x1.x, x1.y, x1.z, x1.w};

    // ---- MLP tower, packed-pair FMA; weights via uniform scalar loads ----
    float h1[16], h2a[16], h3[12], h4[8], h5[4], h6[4];
    layer_pk<8, 16, true, true>(w_fm, b_fm, xin, h1);
    layer_pk<16, 16, true, true>(w_c1, b_c1, h1, h2a);
    layer_pk<16, 12, true, true>(w_p1, b_p1, h2a, h3);
    layer_pk<12, 8, true, true>(w_c2, b_c2, h3, h4);
    layer_pk<8, 4, true, true>(w_p2, b_p2, h4, h5);
    layer_pk<4, 4, true, true>(w_c3, b_c3, h5, h6);

    float qv[4], kk[4];
    layer_pk<4, 4, false, false>(w_q, nullptr, h6, qv);
    layer_pk<4, 4, false, false>(w_k, nullptr, h6, kk);

    // ---- fc folded into V: u = (w_fc^T W_v) . h6 (uniform weights) ----
    float wf[4];
    #pragma unroll
    for (int i = 0; i < 4; ++i)
        wf[i] = fmaf(w_fc[0], w_v[0 * 4 + i],
                fmaf(w_fc[1], w_v[1 * 4 + i],
                fmaf(w_fc[2], w_v[2 * 4 + i], w_fc[3] * w_v[3 * 4 + i])));
    float u = fmaf(wf[0], h6[0], fmaf(wf[1], h6[1], fmaf(wf[2], h6[2], wf[3] * h6[3])));

    h2 pk01 = {(_Float16)kk[0], (_Float16)kk[1]};
    h2 pk23 = {(_Float16)kk[2], (_Float16)kk[3]};
    uint4 ent;
    ent.x = __builtin_bit_cast(unsigned, pk01);
    ent.y = __builtin_bit_cast(unsigned, pk23);
    ent.z = __builtin_bit_cast(unsigned, u);
    ent.w = 0;
    kvbuf[bb][tok] = ent;

    // q scaled by log2(e)/sqrt(4): folds softmax scale and exp->exp2
    const float QS = 0.7213475204f;
    h2 q01 = {(_Float16)(qv[0] * QS), (_Float16)(qv[1] * QS)};
    h2 q23 = {(_Float16)(qv[2] * QS), (_Float16)(qv[3] * QS)};

    __syncthreads();

    // ---- attention: adjacent-lane pair covers rows {tok&~1, tok|1};
    //      parity picks the j-half; combine via shfl_xor(1) ----
    unsigned q01u = __builtin_bit_cast(unsigned, q01);
    unsigned q23u = __builtin_bit_cast(unsigned, q23);
    unsigned q01o = __shfl_xor(q01u, 1);
    unsigned q23o = __shfl_xor(q23u, 1);
    const bool odd = (t & 1);
    h2 q01_r0 = __builtin_bit_cast(h2, odd ? q01o : q01u);
    h2 q23_r0 = __builtin_bit_cast(h2, odd ? q23o : q23u);
    h2 q01_r1 = __builtin_bit_cast(h2, odd ? q01u : q01o);
    h2 q23_r1 = __builtin_bit_cast(h2, odd ? q23u : q23o);

    const uint4* __restrict__ base = kvbuf[bb] + (odd ? 64 : 0);
    float d0 = 0.f, d1 = 0.f, s0acc = 0.f, s1acc = 0.f;
    #pragma unroll 8
    for (int j = 0; j < 64; ++j) {
        uint4 c = base[j];       // 2 addresses/wave -> free broadcast
        h2 k01 = __builtin_bit_cast(h2, c.x);
        h2 k23 = __builtin_bit_cast(h2, c.y);
        float uj = __builtin_bit_cast(float, c.z);
        float s0 = dot2acc(q01_r0, k01, dot2acc(q23_r0, k23, 0.f));
        float s1 = dot2acc(q01_r1, k01, dot2acc(q23_r1, k23, 0.f));
        float e0 = fexp2(s0);
        float e1 = fexp2(s1);
        d0 += e0;                 d1 += e1;
        s0acc = fmaf(e0, uj, s0acc);
        s1acc = fmaf(e1, uj, s1acc);
    }
    d0    += __shfl_xor(d0, 1);    d1    += __shfl_xor(d1, 1);
    s0acc += __shfl_xor(s0acc, 1); s1acc += __shfl_xor(s1acc, 1);

    float dd = odd ? d1 : d0;
    float uu = odd ? s1acc : s0acc;
    float z = uu * fast_rcp(dd) + b_fc[0];
    out[(size_t)batch * 128 + tok] = fast_sigmoid(z);
}

extern "C" void kernel_launch(void* const* d_in, const int* in_sizes, int n_in,
                              void* d_out, int out_size, void* d_ws, size_t ws_size,
                              hipStream_t stream) {
    const float* x    = (const float*)d_in[0];
    const float* w_fm = (const float*)d_in[1];
    const float* b_fm = (const float*)d_in[2];
    const float* w_c1 = (const float*)d_in[3];
    const float* b_c1 = (const float*)d_in[4];
    const float* w_p1 = (const float*)d_in[5];
    const float* b_p1 = (const float*)d_in[6];
    const float* w_c2 = (const float*)d_in[7];
    const float* b_c2 = (const float*)d_in[8];
    const float* w_p2 = (const float*)d_in[9];
    const float* b_p2 = (const float*)d_in[10];
    const float* w_c3 = (const float*)d_in[11];
    const float* b_c3 = (const float*)d_in[12];
    const float* w_q  = (const float*)d_in[13];
    const float* w_k  = (const float*)d_in[14];
    const float* w_v  = (const float*)d_in[15];
    const float* w_fc = (const float*)d_in[16];
    const float* b_fc = (const float*)d_in[17];
    float* out = (float*)d_out;

    dim3 grid(512);    // 4 batches per workgroup
    dim3 block(512);
    qcnn_fused_kernel<<<grid, block, 0, stream>>>(
        x, w_fm, b_fm, w_c1, b_c1, w_p1, b_p1, w_c2, b_c2,
        w_p2, b_p2, w_c3, b_c3, w_q, w_k, w_v, w_fc, b_fc, out);
}

// Round 7
// 22.205 us; speedup vs baseline: 1.0102x; 1.0102x over previous
//
#include <hip/hip_runtime.h>

#define DEV __device__ __forceinline__

typedef _Float16 h2 __attribute__((ext_vector_type(2)));

DEV float fast_rcp(float x) { return __builtin_amdgcn_rcpf(x); }

DEV float fexp2(float x) {
#if __has_builtin(__builtin_amdgcn_exp2f)
    return __builtin_amdgcn_exp2f(x);
#else
    float r; asm("v_exp_f32 %0, %1" : "=v"(r) : "v"(x)); return r;
#endif
}

DEV float dot2acc(h2 a, h2 b, float c) {
#if __has_builtin(__builtin_amdgcn_fdot2)
    return __builtin_amdgcn_fdot2(a, b, c, false);
#else
    return c + (float)a.x * (float)b.x + (float)a.y * (float)b.y;
#endif
}

// tanh(x) = 1 - 2/(exp2(2*log2e*x)+1); saturates correctly at +/-inf.
DEV float fast_tanh(float x) {
    float e = fexp2(x * 2.885390082f);
    return 1.0f - 2.0f * fast_rcp(e + 1.0f);
}
DEV float fast_sigmoid(float x) {
    return fast_rcp(1.0f + fexp2(x * -1.442695041f));
}

template <int IN, int OUT, bool HAS_BIAS, bool TANH>
DEV void layer(const float* __restrict__ w, const float* __restrict__ b,
               const float (&in)[IN], float (&out)[OUT]) {
    #pragma unroll
    for (int o = 0; o < OUT; ++o) {
        float acc = HAS_BIAS ? b[o] : 0.0f;
        #pragma unroll
        for (int i = 0; i < IN; ++i) acc = fmaf(in[i], w[o * IN + i], acc);
        out[o] = TANH ? fast_tanh(acc) : acc;
    }
}

// Full per-token pipeline up to (q packed fp16, kv-entry). wf = folded w_fc^T W_v.
DEV void token_head(const float (&xin)[8],
                    const float* __restrict__ w_fm, const float* __restrict__ b_fm,
                    const float* __restrict__ w_c1, const float* __restrict__ b_c1,
                    const float* __restrict__ w_p1, const float* __restrict__ b_p1,
                    const float* __restrict__ w_c2, const float* __restrict__ b_c2,
                    const float* __restrict__ w_p2, const float* __restrict__ b_p2,
                    const float* __restrict__ w_c3, const float* __restrict__ b_c3,
                    const float* __restrict__ w_q,  const float* __restrict__ w_k,
                    const float (&wf)[4],
                    h2& q01, h2& q23, uint4& ent) {
    float h1[16], h2a[16], h3[12], h4[8], h5[4], h6[4];
    layer<8, 16, true, true>(w_fm, b_fm, xin, h1);
    layer<16, 16, true, true>(w_c1, b_c1, h1, h2a);
    layer<16, 12, true, true>(w_p1, b_p1, h2a, h3);
    layer<12, 8, true, true>(w_c2, b_c2, h3, h4);
    layer<8, 4, true, true>(w_p2, b_p2, h4, h5);
    layer<4, 4, true, true>(w_c3, b_c3, h5, h6);

    float qv[4], kk[4];
    layer<4, 4, false, false>(w_q, nullptr, h6, qv);
    layer<4, 4, false, false>(w_k, nullptr, h6, kk);
    float u = fmaf(wf[0], h6[0], fmaf(wf[1], h6[1], fmaf(wf[2], h6[2], wf[3] * h6[3])));

    h2 pk01 = {(_Float16)kk[0], (_Float16)kk[1]};
    h2 pk23 = {(_Float16)kk[2], (_Float16)kk[3]};
    ent.x = __builtin_bit_cast(unsigned, pk01);
    ent.y = __builtin_bit_cast(unsigned, pk23);
    ent.z = __builtin_bit_cast(unsigned, u);
    ent.w = 0;

    const float QS = 0.7213475204f;  // log2(e)/sqrt(4)
    q01 = h2{(_Float16)(qv[0] * QS), (_Float16)(qv[1] * QS)};
    q23 = h2{(_Float16)(qv[2] * QS), (_Float16)(qv[3] * QS)};
}

__global__ __launch_bounds__(256)
void qcnn_fused_kernel(const float* __restrict__ x,
                       const float* __restrict__ w_fm, const float* __restrict__ b_fm,
                       const float* __restrict__ w_c1, const float* __restrict__ b_c1,
                       const float* __restrict__ w_p1, const float* __restrict__ b_p1,
                       const float* __restrict__ w_c2, const float* __restrict__ b_c2,
                       const float* __restrict__ w_p2, const float* __restrict__ b_p2,
                       const float* __restrict__ w_c3, const float* __restrict__ b_c3,
                       const float* __restrict__ w_q,  const float* __restrict__ w_k,
                       const float* __restrict__ w_v,
                       const float* __restrict__ w_fc, const float* __restrict__ b_fc,
                       float* __restrict__ out) {
    const int t     = threadIdx.x;          // 0..255
    const int bb    = t >> 6;               // sub-batch 0..3 == wave id
    const int lane  = t & 63;
    const int batch = blockIdx.x * 4 + bb;  // 0..2047

    // per-sub-batch KV: x=k01(fp16x2) y=k23(fp16x2) z=u(f32) w=pad
    __shared__ uint4 kvbuf[4][128];

    // folded fc.V weights (uniform, 16 FMA)
    float wf[4];
    #pragma unroll
    for (int i = 0; i < 4; ++i)
        wf[i] = fmaf(w_fc[0], w_v[0 * 4 + i],
                fmaf(w_fc[1], w_v[1 * 4 + i],
                fmaf(w_fc[2], w_v[2 * 4 + i], w_fc[3] * w_v[3 * 4 + i])));

    // ---- two tokens per thread: lane and lane+64 (independent MLP chains) ----
    const float* xpA = x + ((size_t)batch * 128 + lane) * 8;
    const float* xpB = xpA + 64 * 8;
    float4 a0 = *reinterpret_cast<const float4*>(xpA);
    float4 a1 = *reinterpret_cast<const float4*>(xpA + 4);
    float4 b0 = *reinterpret_cast<const float4*>(xpB);
    float4 b1 = *reinterpret_cast<const float4*>(xpB + 4);
    float xA[8] = {a0.x, a0.y, a0.z, a0.w, a1.x, a1.y, a1.z, a1.w};
    float xB[8] = {b0.x, b0.y, b0.z, b0.w, b1.x, b1.y, b1.z, b1.w};

    h2 qA01, qA23, qB01, qB23;
    uint4 entA, entB;
    token_head(xA, w_fm, b_fm, w_c1, b_c1, w_p1, b_p1, w_c2, b_c2,
               w_p2, b_p2, w_c3, b_c3, w_q, w_k, wf, qA01, qA23, entA);
    token_head(xB, w_fm, b_fm, w_c1, b_c1, w_p1, b_p1, w_c2, b_c2,
               w_p2, b_p2, w_c3, b_c3, w_q, w_k, wf, qB01, qB23, entB);

    kvbuf[bb][lane]      = entA;
    kvbuf[bb][lane + 64] = entB;
    __syncthreads();

    // ---- attention: each thread owns full rows lane and lane+64.
    //      kvbuf[bb][j] is wave-uniform -> 1-address LDS broadcast. ----
    float dA = 0.f, dB = 0.f, uA = 0.f, uB = 0.f;
    #pragma unroll 8
    for (int j = 0; j < 128; ++j) {
        uint4 c = kvbuf[bb][j];
        h2 k01 = __builtin_bit_cast(h2, c.x);
        h2 k23 = __builtin_bit_cast(h2, c.y);
        float uj = __builtin_bit_cast(float, c.z);
        float sA = dot2acc(qA01, k01, dot2acc(qA23, k23, 0.f));
        float sB = dot2acc(qB01, k01, dot2acc(qB23, k23, 0.f));
        float eA = fexp2(sA);
        float eB = fexp2(sB);
        dA += eA;  dB += eB;
        uA = fmaf(eA, uj, uA);
        uB = fmaf(eB, uj, uB);
    }

    float zA = uA * fast_rcp(dA) + b_fc[0];
    float zB = uB * fast_rcp(dB) + b_fc[0];
    float* op = out + (size_t)batch * 128 + lane;
    op[0]  = fast_sigmoid(zA);
    op[64] = fast_sigmoid(zB);
}

extern "C" void kernel_launch(void* const* d_in, const int* in_sizes, int n_in,
                              void* d_out, int out_size, void* d_ws, size_t ws_size,
                              hipStream_t stream) {
    const float* x    = (const float*)d_in[0];
    const float* w_fm = (const float*)d_in[1];
    const float* b_fm = (const float*)d_in[2];
    const float* w_c1 = (const float*)d_in[3];
    const float* b_c1 = (const float*)d_in[4];
    const float* w_p1 = (const float*)d_in[5];
    const float* b_p1 = (const float*)d_in[6];
    const float* w_c2 = (const float*)d_in[7];
    const float* b_c2 = (const float*)d_in[8];
    const float* w_p2 = (const float*)d_in[9];
    const float* b_p2 = (const float*)d_in[10];
    const float* w_c3 = (const float*)d_in[11];
    const float* b_c3 = (const float*)d_in[12];
    const float* w_q  = (const float*)d_in[13];
    const float* w_k  = (const float*)d_in[14];
    const float* w_v  = (const float*)d_in[15];
    const float* w_fc = (const float*)d_in[16];
    const float* b_fc = (const float*)d_in[17];
    float* out = (float*)d_out;

    dim3 grid(512);    // 4 batches per workgroup, wave-aligned sub-batches
    dim3 block(256);   // 2 tokens per thread
    qcnn_fused_kernel<<<grid, block, 0, stream>>>(
        x, w_fm, b_fm, w_c1, b_c1, w_p1, b_p1, w_c2, b_c2,
        w_p2, b_p2, w_c3, b_c3, w_q, w_k, w_v, w_fc, b_fc, out);
}

// Round 8
// 20.612 us; speedup vs baseline: 1.0883x; 1.0773x over previous
//
#include <hip/hip_runtime.h>

#define DEV __device__ __forceinline__

typedef _Float16 h2 __attribute__((ext_vector_type(2)));
typedef float    f2 __attribute__((ext_vector_type(2)));

DEV float fast_rcp(float x) { return __builtin_amdgcn_rcpf(x); }

DEV float fexp2(float x) {
#if __has_builtin(__builtin_amdgcn_exp2f)
    return __builtin_amdgcn_exp2f(x);
#else
    float r; asm("v_exp_f32 %0, %1" : "=v"(r) : "v"(x)); return r;
#endif
}

DEV float dot2acc(h2 a, h2 b, float c) {
#if __has_builtin(__builtin_amdgcn_fdot2)
    return __builtin_amdgcn_fdot2(a, b, c, false);
#else
    return c + (float)a.x * (float)b.x + (float)a.y * (float)b.y;
#endif
}

// acc = w2 * in2 + acc, packed f32 (one instr, 2 FMAs). w2 comes from a
// uniform address -> SGPR pair ("s" constraint; VOP3P allows one SGPR src).
DEV void pk_fma(f2& acc, f2 w2, f2 in2) {
    asm("v_pk_fma_f32 %0, %1, %2, %0" : "+v"(acc) : "s"(w2), "v"(in2));
}

// tanh(x) = 1 - 2/(exp2(2*log2e*x)+1); saturates correctly at +/-inf.
DEV float fast_tanh(float x) {
    float e = fexp2(x * 2.885390082f);
    return 1.0f - 2.0f * fast_rcp(e + 1.0f);
}
DEV float fast_sigmoid(float x) {
    return fast_rcp(1.0f + fexp2(x * -1.442695041f));
}

// MLP layer, input-pair packed: (w[o][2i], w[o][2i+1]) is contiguous in the
// row-major weights -> uniform s_load_dwordx2 feeds v_pk_fma_f32 directly.
template <int IN, int OUT, bool HAS_BIAS, bool TANH>
DEV void layer_pk(const float* __restrict__ w, const float* __restrict__ b,
                  const float (&in)[IN], float (&out)[OUT]) {
    static_assert(IN % 2 == 0, "IN must be even");
    f2 in2[IN / 2];
    #pragma unroll
    for (int ip = 0; ip < IN / 2; ++ip) in2[ip] = f2{in[2 * ip], in[2 * ip + 1]};
    #pragma unroll
    for (int o = 0; o < OUT; ++o) {
        f2 acc = {HAS_BIAS ? b[o] : 0.0f, 0.0f};
        #pragma unroll
        for (int ip = 0; ip < IN / 2; ++ip) {
            f2 w2 = *reinterpret_cast<const f2*>(w + o * IN + 2 * ip);
            pk_fma(acc, w2, in2[ip]);
        }
        float s = acc.x + acc.y;
        out[o] = TANH ? fast_tanh(s) : s;
    }
}

__global__ __launch_bounds__(256)
void qcnn_fused_kernel(const float* __restrict__ x,
                       const float* __restrict__ w_fm, const float* __restrict__ b_fm,
                       const float* __restrict__ w_c1, const float* __restrict__ b_c1,
                       const float* __restrict__ w_p1, const float* __restrict__ b_p1,
                       const float* __restrict__ w_c2, const float* __restrict__ b_c2,
                       const float* __restrict__ w_p2, const float* __restrict__ b_p2,
                       const float* __restrict__ w_c3, const float* __restrict__ b_c3,
                       const float* __restrict__ w_q,  const float* __restrict__ w_k,
                       const float* __restrict__ w_v,
                       const float* __restrict__ w_fc, const float* __restrict__ b_fc,
                       float* __restrict__ out) {
    const int t     = threadIdx.x;          // 0..255
    const int bb    = t >> 7;               // sub-batch 0/1 within block
    const int tok   = t & 127;              // token 0..127
    const int batch = blockIdx.x * 2 + bb;  // 0..2047

    // per-sub-batch KV: x=k01(fp16x2) y=k23(fp16x2) z=u(f32) w=pad
    __shared__ uint4 kvbuf[2][128];

    // ---- load x[batch][tok][0:8] (coalesced, 32 B/thread) ----
    const float* xp = x + ((size_t)batch * 128 + tok) * 8;
    float4 x0 = *reinterpret_cast<const float4*>(xp);
    float4 x1 = *reinterpret_cast<const float4*>(xp + 4);
    float xin[8] = {x0.x, x0.y, x0.z, x0.w, x1.x, x1.y, x1.z, x1.w};

    // ---- MLP tower, packed-pair f32 FMA; weights via uniform scalar loads ----
    float h1[16], h2a[16], h3[12], h4[8], h5[4], h6[4];
    layer_pk<8, 16, true, true>(w_fm, b_fm, xin, h1);
    layer_pk<16, 16, true, true>(w_c1, b_c1, h1, h2a);
    layer_pk<16, 12, true, true>(w_p1, b_p1, h2a, h3);
    layer_pk<12, 8, true, true>(w_c2, b_c2, h3, h4);
    layer_pk<8, 4, true, true>(w_p2, b_p2, h4, h5);
    layer_pk<4, 4, true, true>(w_c3, b_c3, h5, h6);

    float qv[4], kk[4];
    layer_pk<4, 4, false, false>(w_q, nullptr, h6, qv);
    layer_pk<4, 4, false, false>(w_k, nullptr, h6, kk);

    // ---- fc folded into V: u = (w_fc^T W_v) . h6 (uniform weights) ----
    float wf[4];
    #pragma unroll
    for (int i = 0; i < 4; ++i)
        wf[i] = fmaf(w_fc[0], w_v[0 * 4 + i],
                fmaf(w_fc[1], w_v[1 * 4 + i],
                fmaf(w_fc[2], w_v[2 * 4 + i], w_fc[3] * w_v[3 * 4 + i])));
    float u = fmaf(wf[0], h6[0], fmaf(wf[1], h6[1], fmaf(wf[2], h6[2], wf[3] * h6[3])));

    h2 pk01 = {(_Float16)kk[0], (_Float16)kk[1]};
    h2 pk23 = {(_Float16)kk[2], (_Float16)kk[3]};
    uint4 ent;
    ent.x = __builtin_bit_cast(unsigned, pk01);
    ent.y = __builtin_bit_cast(unsigned, pk23);
    ent.z = __builtin_bit_cast(unsigned, u);
    ent.w = 0;
    kvbuf[bb][tok] = ent;

    // q scaled by log2(e)/sqrt(4): folds softmax scale and exp->exp2
    const float QS = 0.7213475204f;
    h2 q01 = {(_Float16)(qv[0] * QS), (_Float16)(qv[1] * QS)};
    h2 q23 = {(_Float16)(qv[2] * QS), (_Float16)(qv[3] * QS)};

    __syncthreads();

    // ---- attention: adjacent-lane pair covers rows {tok&~1, tok|1};
    //      parity picks the j-half; combine via shfl_xor(1) ----
    unsigned q01u = __builtin_bit_cast(unsigned, q01);
    unsigned q23u = __builtin_bit_cast(unsigned, q23);
    unsigned q01o = __shfl_xor(q01u, 1);
    unsigned q23o = __shfl_xor(q23u, 1);
    const bool odd = (t & 1);
    h2 q01_r0 = __builtin_bit_cast(h2, odd ? q01o : q01u);
    h2 q23_r0 = __builtin_bit_cast(h2, odd ? q23o : q23u);
    h2 q01_r1 = __builtin_bit_cast(h2, odd ? q01u : q01o);
    h2 q23_r1 = __builtin_bit_cast(h2, odd ? q23u : q23o);

    const uint4* __restrict__ base = kvbuf[bb] + (odd ? 64 : 0);
    float d0 = 0.f, d1 = 0.f, s0acc = 0.f, s1acc = 0.f;
    #pragma unroll 8
    for (int j = 0; j < 64; ++j) {
        uint4 c = base[j];       // 2 addresses/wave -> free broadcast
        h2 k01 = __builtin_bit_cast(h2, c.x);
        h2 k23 = __builtin_bit_cast(h2, c.y);
        float uj = __builtin_bit_cast(float, c.z);
        float s0 = dot2acc(q01_r0, k01, dot2acc(q23_r0, k23, 0.f));
        float s1 = dot2acc(q01_r1, k01, dot2acc(q23_r1, k23, 0.f));
        float e0 = fexp2(s0);
        float e1 = fexp2(s1);
        d0 += e0;                 d1 += e1;
        s0acc = fmaf(e0, uj, s0acc);
        s1acc = fmaf(e1, uj, s1acc);
    }
    d0    += __shfl_xor(d0, 1);    d1    += __shfl_xor(d1, 1);
    s0acc += __shfl_xor(s0acc, 1); s1acc += __shfl_xor(s1acc, 1);

    float dd = odd ? d1 : d0;
    float uu = odd ? s1acc : s0acc;
    float z = uu * fast_rcp(dd) + b_fc[0];
    out[(size_t)batch * 128 + tok] = fast_sigmoid(z);
}

extern "C" void kernel_launch(void* const* d_in, const int* in_sizes, int n_in,
                              void* d_out, int out_size, void* d_ws, size_t ws_size,
                              hipStream_t stream) {
    const float* x    = (const float*)d_in[0];
    const float* w_fm = (const float*)d_in[1];
    const float* b_fm = (const float*)d_in[2];
    const float* w_c1 = (const float*)d_in[3];
    const float* b_c1 = (const float*)d_in[4];
    const float* w_p1 = (const float*)d_in[5];
    const float* b_p1 = (const float*)d_in[6];
    const float* w_c2 = (const float*)d_in[7];
    const float* b_c2 = (const float*)d_in[8];
    const float* w_p2 = (const float*)d_in[9];
    const float* b_p2 = (const float*)d_in[10];
    const float* w_c3 = (const float*)d_in[11];
    const float* b_c3 = (const float*)d_in[12];
    const float* w_q  = (const float*)d_in[13];
    const float* w_k  = (const float*)d_in[14];
    const float* w_v  = (const float*)d_in[15];
    const float* w_fc = (const float*)d_in[16];
    const float* b_fc = (const float*)d_in[17];
    float* out = (float*)d_out;

    dim3 grid(1024);   // 2 batches per workgroup (R5 frontier config)
    dim3 block(256);
    qcnn_fused_kernel<<<grid, block, 0, stream>>>(
        x, w_fm, b_fm, w_c1, b_c1, w_p1, b_p1, w_c2, b_c2,
        w_p2, b_p2, w_c3, b_c3, w_q, w_k, w_v, w_fc, b_fc, out);
}

// Round 9
// 20.235 us; speedup vs baseline: 1.1086x; 1.0186x over previous
//
#include <hip/hip_runtime.h>

#define DEV __device__ __forceinline__

typedef _Float16 h2 __attribute__((ext_vector_type(2)));
typedef float    f2 __attribute__((ext_vector_type(2)));

DEV float fast_rcp(float x) { return __builtin_amdgcn_rcpf(x); }

DEV float fexp2(float x) {
#if __has_builtin(__builtin_amdgcn_exp2f)
    return __builtin_amdgcn_exp2f(x);
#else
    float r; asm("v_exp_f32 %0, %1" : "=v"(r) : "v"(x)); return r;
#endif
}

DEV float dot2acc(h2 a, h2 b, float c) {
#if __has_builtin(__builtin_amdgcn_fdot2)
    return __builtin_amdgcn_fdot2(a, b, c, false);
#else
    return c + (float)a.x * (float)b.x + (float)a.y * (float)b.y;
#endif
}

// acc = w2 * in2 + acc (packed f32). w2 uniform -> SGPR pair.
DEV void pk_fma(f2& acc, f2 w2, f2 in2) {
    asm("v_pk_fma_f32 %0, %1, %2, %0" : "+v"(acc) : "s"(w2), "v"(in2));
}
// acc = w2 * in2 + 0  (inline-0 C: no accumulator init movs).
DEV f2 pk_fma_z(f2 w2, f2 in2) {
    f2 d;
    asm("v_pk_fma_f32 %0, %1, %2, 0 op_sel_hi:[1,1,0]"
        : "=v"(d) : "s"(w2), "v"(in2));
    return d;
}
// acc += broadcast(e.x) * du   (du = {1.0, u} pair straight from LDS).
// op_sel_hi[0]=0 -> hi result reads lo word of src0 (e broadcast, hi undef ok).
DEV void pk_fma_bcast(f2& acc, f2 e, f2 du) {
    asm("v_pk_fma_f32 %0, %1, %2, %0 op_sel:[0,0,0] op_sel_hi:[0,1,1]"
        : "+v"(acc) : "v"(e), "v"(du));
}

// tanh from pre-scaled input t = 2*log2(e)*(Wx+b): 1 - 2/(exp2(t)+1).
DEV float fast_tanh_pre(float t) {
    float e = fexp2(t);
    return 1.0f - 2.0f * fast_rcp(e + 1.0f);
}
DEV float fast_sigmoid(float x) {
    return fast_rcp(1.0f + fexp2(x * -1.442695041f));
}

#define TANH_K 2.885390082f   // 2*log2(e)

// MLP layer, input-pair packed weights via uniform s_load_dwordx2.
// Bias folded into the tanh-input FMA: t = dot*K + (b*K).
template <int IN, int OUT, bool TANH>
DEV void layer_pk(const float* __restrict__ w, const float* __restrict__ b,
                  float vK, const float (&in)[IN], float (&out)[OUT]) {
    static_assert(IN % 2 == 0, "IN must be even");
    f2 in2[IN / 2];
    #pragma unroll
    for (int ip = 0; ip < IN / 2; ++ip) in2[ip] = f2{in[2 * ip], in[2 * ip + 1]};
    #pragma unroll
    for (int o = 0; o < OUT; ++o) {
        f2 acc = pk_fma_z(*reinterpret_cast<const f2*>(w + o * IN), in2[0]);
        #pragma unroll
        for (int ip = 1; ip < IN / 2; ++ip)
            pk_fma(acc, *reinterpret_cast<const f2*>(w + o * IN + 2 * ip), in2[ip]);
        float s = acc.x + acc.y;
        if (TANH) {
            float bk = b[o] * vK;           // v_mul: sgpr bias x vgpr K
            out[o] = fast_tanh_pre(fmaf(s, vK, bk));
        } else {
            out[o] = s;
        }
    }
}

__global__ __launch_bounds__(256)
void qcnn_fused_kernel(const float* __restrict__ x,
                       const float* __restrict__ w_fm, const float* __restrict__ b_fm,
                       const float* __restrict__ w_c1, const float* __restrict__ b_c1,
                       const float* __restrict__ w_p1, const float* __restrict__ b_p1,
                       const float* __restrict__ w_c2, const float* __restrict__ b_c2,
                       const float* __restrict__ w_p2, const float* __restrict__ b_p2,
                       const float* __restrict__ w_c3, const float* __restrict__ b_c3,
                       const float* __restrict__ w_q,  const float* __restrict__ w_k,
                       const float* __restrict__ w_v,
                       const float* __restrict__ w_fc, const float* __restrict__ b_fc,
                       float* __restrict__ out) {
    const int t     = threadIdx.x;          // 0..255
    const int bb    = t >> 7;               // sub-batch 0/1 within block
    const int tok   = t & 127;              // token 0..127
    const int batch = blockIdx.x * 2 + bb;  // 0..2047

    // per-token entry: x=k01(fp16x2) y=k23(fp16x2) z=1.0f w=u(f32)
    __shared__ uint4 kvbuf[2][128];

    const float vK = TANH_K;                // hoisted VGPR constant

    // ---- load x[batch][tok][0:8] (coalesced, 32 B/thread) ----
    const float* xp = x + ((size_t)batch * 128 + tok) * 8;
    float4 x0 = *reinterpret_cast<const float4*>(xp);
    float4 x1 = *reinterpret_cast<const float4*>(xp + 4);
    float xin[8] = {x0.x, x0.y, x0.z, x0.w, x1.x, x1.y, x1.z, x1.w};

    // ---- MLP tower, packed-pair f32 FMA; weights via uniform scalar loads ----
    float h1[16], h2a[16], h3[12], h4[8], h5[4], h6[4];
    layer_pk<8, 16, true>(w_fm, b_fm, vK, xin, h1);
    layer_pk<16, 16, true>(w_c1, b_c1, vK, h1, h2a);
    layer_pk<16, 12, true>(w_p1, b_p1, vK, h2a, h3);
    layer_pk<12, 8, true>(w_c2, b_c2, vK, h3, h4);
    layer_pk<8, 4, true>(w_p2, b_p2, vK, h4, h5);
    layer_pk<4, 4, true>(w_c3, b_c3, vK, h5, h6);

    float qv[4], kk[4];
    layer_pk<4, 4, false>(w_q, nullptr, vK, h6, qv);
    layer_pk<4, 4, false>(w_k, nullptr, vK, h6, kk);

    // ---- fc folded into V: u = (w_fc^T W_v) . h6 (uniform weights) ----
    float wf[4];
    #pragma unroll
    for (int i = 0; i < 4; ++i)
        wf[i] = fmaf(w_fc[0], w_v[0 * 4 + i],
                fmaf(w_fc[1], w_v[1 * 4 + i],
                fmaf(w_fc[2], w_v[2 * 4 + i], w_fc[3] * w_v[3 * 4 + i])));
    float u = fmaf(wf[0], h6[0], fmaf(wf[1], h6[1], fmaf(wf[2], h6[2], wf[3] * h6[3])));

    h2 pk01 = {(_Float16)kk[0], (_Float16)kk[1]};
    h2 pk23 = {(_Float16)kk[2], (_Float16)kk[3]};
    uint4 ent;
    ent.x = __builtin_bit_cast(unsigned, pk01);
    ent.y = __builtin_bit_cast(unsigned, pk23);
    ent.z = __builtin_bit_cast(unsigned, 1.0f);   // pairs with u for pk_fma
    ent.w = __builtin_bit_cast(unsigned, u);
    kvbuf[bb][tok] = ent;

    // q scaled by log2(e)/sqrt(4): folds softmax scale and exp->exp2
    const float QS = 0.7213475204f;
    h2 q01 = {(_Float16)(qv[0] * QS), (_Float16)(qv[1] * QS)};
    h2 q23 = {(_Float16)(qv[2] * QS), (_Float16)(qv[3] * QS)};

    __syncthreads();

    // ---- attention: adjacent-lane pair covers rows {tok&~1, tok|1};
    //      parity picks the j-half; combine via shfl_xor(1) ----
    unsigned q01u = __builtin_bit_cast(unsigned, q01);
    unsigned q23u = __builtin_bit_cast(unsigned, q23);
    unsigned q01o = __shfl_xor(q01u, 1);
    unsigned q23o = __shfl_xor(q23u, 1);
    const bool odd = (t & 1);
    h2 q01_r0 = __builtin_bit_cast(h2, odd ? q01o : q01u);
    h2 q23_r0 = __builtin_bit_cast(h2, odd ? q23o : q23u);
    h2 q01_r1 = __builtin_bit_cast(h2, odd ? q01u : q01o);
    h2 q23_r1 = __builtin_bit_cast(h2, odd ? q23u : q23o);

    const uint4* __restrict__ base = kvbuf[bb] + (odd ? 64 : 0);
    f2 acc0 = {0.f, 0.f};   // {denom, numerator} for row r0 (this lane's j-half)
    f2 acc1 = {0.f, 0.f};   // same for row r1
    #pragma unroll 8
    for (int j = 0; j < 64; ++j) {
        uint4 c = base[j];       // 2 addresses/wave -> free broadcast
        h2 k01 = __builtin_bit_cast(h2, c.x);
        h2 k23 = __builtin_bit_cast(h2, c.y);
        f2 du;                   // {1.0, u} directly from the b128 read
        du.x = __builtin_bit_cast(float, c.z);
        du.y = __builtin_bit_cast(float, c.w);
        float s0 = dot2acc(q01_r0, k01, dot2acc(q23_r0, k23, 0.f));
        float s1 = dot2acc(q01_r1, k01, dot2acc(q23_r1, k23, 0.f));
        f2 e0; e0.x = fexp2(s0);          // hi word intentionally undef
        f2 e1; e1.x = fexp2(s1);
        pk_fma_bcast(acc0, e0, du);       // {d,n} += e * {1, u}
        pk_fma_bcast(acc1, e1, du);
    }

    // combine lane-pair partials (each row's j-halves in adjacent lanes)
    f2 p0, p1;
    p0.x = __shfl_xor(acc0.x, 1);  p0.y = __shfl_xor(acc0.y, 1);
    p1.x = __shfl_xor(acc1.x, 1);  p1.y = __shfl_xor(acc1.y, 1);
    acc0 += p0;
    acc1 += p1;

    float dd = odd ? acc1.x : acc0.x;
    float uu = odd ? acc1.y : acc0.y;
    float z = fmaf(uu, fast_rcp(dd), b_fc[0]);
    out[(size_t)batch * 128 + tok] = fast_sigmoid(z);
}

extern "C" void kernel_launch(void* const* d_in, const int* in_sizes, int n_in,
                              void* d_out, int out_size, void* d_ws, size_t ws_size,
                              hipStream_t stream) {
    const float* x    = (const float*)d_in[0];
    const float* w_fm = (const float*)d_in[1];
    const float* b_fm = (const float*)d_in[2];
    const float* w_c1 = (const float*)d_in[3];
    const float* b_c1 = (const float*)d_in[4];
    const float* w_p1 = (const float*)d_in[5];
    const float* b_p1 = (const float*)d_in[6];
    const float* w_c2 = (const float*)d_in[7];
    const float* b_c2 = (const float*)d_in[8];
    const float* w_p2 = (const float*)d_in[9];
    const float* b_p2 = (const float*)d_in[10];
    const float* w_c3 = (const float*)d_in[11];
    const float* b_c3 = (const float*)d_in[12];
    const float* w_q  = (const float*)d_in[13];
    const float* w_k  = (const float*)d_in[14];
    const float* w_v  = (const float*)d_in[15];
    const float* w_fc = (const float*)d_in[16];
    const float* b_fc = (const float*)d_in[17];
    float* out = (float*)d_out;

    dim3 grid(1024);   // 2 batches per workgroup (R5/R8 frontier config)
    dim3 block(256);
    qcnn_fused_kernel<<<grid, block, 0, stream>>>(
        x, w_fm, b_fm, w_c1, b_c1, w_p1, b_p1, w_c2, b_c2,
        w_p2, b_p2, w_c3, b_c3, w_q, w_k, w_v, w_fc, b_fc, out);
}